// Round 9
// baseline (274.167 us; speedup 1.0000x reference)
//
#include <hip/hip_runtime.h>
#include <math.h>

#define DIM 512
#define INTER 64
#define N_ROUTED 64
#define TOPK 6
#define NTOK 1024            // B*T
#define TTILE 8              // tokens per ffn tile
#define GR 16                // blocks per routed expert (64*16 = 1024)
#define GS 128               // blocks per shared expert (2*128 = 256)
#define CHN (NTOK * TOPK)    // 6144 dense choice entries
#define CHUNK (CHN / 256)    // 24 entries per thread in the list scan

// ---------------------------------------------------------------------------
// Gate (dispatch 1 of 2): 4 tokens per block, 256 blocks.
//  - zeroes its 4 output rows (replaces memset dispatch)
//  - lane holds x[t][lane*4..] / x[t][256+lane*4..] for 4 tokens in regs;
//    wave w computes experts [w*16,w*16+16) for all 4 tokens via coalesced
//    g_w ROW loads + butterfly reduce (g_w L2 traffic 32 MB).
//  - wave w then does token (t0+w)'s softmax over 64 experts + iterative
//    top-6 argmax on (prob+bias), first-index tie-break (matches lax.top_k).
// ---------------------------------------------------------------------------
__global__ __launch_bounds__(256) void gate_kernel(
    const float* __restrict__ x, const float* __restrict__ g_w,
    const float* __restrict__ gate_bias,
    int* __restrict__ chidx, float* __restrict__ chw,
    float* __restrict__ out) {
  __shared__ float logits[4][N_ROUTED];
  const int t0 = blockIdx.x * 4;
  const int tid = threadIdx.x;
  const int lane = tid & 63;
  const int w = tid >> 6;

  {
    float4* ob = (float4*)(out + (size_t)t0 * DIM);
    ob[tid] = make_float4(0.f, 0.f, 0.f, 0.f);
    ob[tid + 256] = make_float4(0.f, 0.f, 0.f, 0.f);
  }

  float4 xa[4], xb[4];
  #pragma unroll
  for (int t = 0; t < 4; ++t) {
    const float* xr = x + (size_t)(t0 + t) * DIM;
    xa[t] = *(const float4*)(xr + lane * 4);
    xb[t] = *(const float4*)(xr + 256 + lane * 4);
  }

  #pragma unroll 2
  for (int k = 0; k < 16; ++k) {
    const int e = w * 16 + k;
    const float* gr = g_w + (size_t)e * DIM;
    const float4 ga = *(const float4*)(gr + lane * 4);
    const float4 gb = *(const float4*)(gr + 256 + lane * 4);
    float v[4];
    #pragma unroll
    for (int t = 0; t < 4; ++t)
      v[t] = xa[t].x * ga.x + xa[t].y * ga.y + xa[t].z * ga.z + xa[t].w * ga.w
           + xb[t].x * gb.x + xb[t].y * gb.y + xb[t].z * gb.z + xb[t].w * gb.w;
    #pragma unroll
    for (int t = 0; t < 4; ++t) {
      float s = v[t];
      for (int off = 32; off; off >>= 1) s += __shfl_xor(s, off, 64);
      if (lane == 0) logits[t][e] = s;
    }
  }
  __syncthreads();

  {
    const int t = t0 + w;
    const float a = logits[w][lane];
    float m = a;
    for (int off = 32; off; off >>= 1) m = fmaxf(m, __shfl_xor(m, off, 64));
    const float p = expf(a - m);
    float s = p;
    for (int off = 32; off; off >>= 1) s += __shfl_xor(s, off, 64);
    const float prob = p / s;
    float biased = prob + gate_bias[lane];
    for (int k = 0; k < TOPK; ++k) {
      float v = biased;
      int idx = lane;
      for (int off = 1; off < 64; off <<= 1) {
        const float ov = __shfl_xor(v, off, 64);
        const int oi = __shfl_xor(idx, off, 64);
        if (ov > v || (ov == v && oi < idx)) { v = ov; idx = oi; }
      }
      if (lane == idx) {
        chidx[t * TOPK + k] = lane;
        chw[t * TOPK + k] = prob;      // ROUTE_SCALE == 1.0
        biased = -INFINITY;
      }
    }
  }
}

// ---------------------------------------------------------------------------
// Expert FFN (dispatch 2 of 2): block = (expert, group), XCD-pinned
// (expert r runs only on XCD r%8 via blockIdx&7 round-robin heuristic).
// Routed blocks rebuild their own token sub-list from the dense choices via
// a deterministic block prefix-scan (all GR blocks agree on ranks; block g
// takes ranks == g mod GR). No extra dispatch, no atomics.
// TTILE=8 / GR=16: 1280 blocks -> 5 blocks/CU (20 waves/CU) for latency
// hiding; 18.6 KB LDS; small register arrays (round-8 scratch-spill lesson:
// NO readfirstlane pointer arrays — wave-uniform vector loads are L1-served).
// Phase A: wave w covers d in [w*128,w*128+128) for all 8 tokens (lane =
// inter unit, weights coalesced dword, x wave-uniform float4); cross-wave
// reduce + silu*h3*route_w -> as_; phase B: thread owns output cols
// (tid, tid+256), coalesced atomicAdd into pre-zeroed out. 2 barriers/tile.
// ---------------------------------------------------------------------------
__global__ __launch_bounds__(256, 6) void ffn_kernel(
    const float* __restrict__ x,
    const float* __restrict__ w1, const float* __restrict__ w2,
    const float* __restrict__ w3,
    const int* __restrict__ chidx, const float* __restrict__ chw,
    float* __restrict__ out) {
  __shared__ float part1[4][TTILE][INTER];   // 8 KB
  __shared__ float part3[4][TTILE][INTER];   // 8 KB
  __shared__ float as_[TTILE][INTER];        // 2 KB
  __shared__ int   lTok[64];
  __shared__ float lW[64];
  __shared__ int   waveTot[4];

  const int tid = threadIdx.x;
  const int lane = tid & 63;
  const int w = tid >> 6;
  const int blk = blockIdx.x;

  int e, m;
  if (blk < N_ROUTED * GR) {
    // ---- routed: deterministic sub-list build ----
    const int c = blk & 7;          // XCD residue
    const int q = blk >> 3;         // 0..127
    const int ei = q >> 4;          // 0..7
    const int g = q & 15;           // group within expert (GR=16)
    const int r = ei * 8 + c;       // routed expert id (r%8 == c)
    e = r + 2;

    if (tid < 64) { lTok[tid] = 0; lW[tid] = 0.f; }

    const int j0 = tid * CHUNK;
    int cntL = 0;
    #pragma unroll
    for (int k = 0; k < CHUNK; ++k)
      cntL += (chidx[j0 + k] == r) ? 1 : 0;

    int incl = cntL;                // wave-inclusive prefix
    for (int off = 1; off < 64; off <<= 1) {
      const int v = __shfl_up(incl, off, 64);
      if (lane >= off) incl += v;
    }
    if (lane == 63) waveTot[w] = incl;
    __syncthreads();

    int waveOff = 0, nTot = 0;
    #pragma unroll
    for (int i = 0; i < 4; ++i) {
      const int v = waveTot[i];
      nTot += v;
      if (i < w) waveOff += v;
    }
    int rank = waveOff + incl - cntL;   // exclusive global rank
    for (int k = 0; k < CHUNK; ++k) {
      const int j = j0 + k;
      if (chidx[j] == r) {
        if ((rank & 15) == g) {
          lTok[rank >> 4] = j / TOPK;
          lW[rank >> 4] = chw[j];
        }
        ++rank;
      }
    }
    m = (nTot > g) ? ((nTot - g + GR - 1) >> 4) : 0;
    __syncthreads();
  } else {
    // ---- shared experts: tokens g, g+128, ..., weight 1 ----
    const int sb = blk - N_ROUTED * GR;   // 0..255
    e = sb >> 7;                          // 0..1
    const int g = sb & 127;
    if (tid < 64) {
      lTok[tid] = (tid < 8) ? (g + tid * GS) : 0;
      lW[tid] = (tid < 8) ? 1.0f : 0.f;
    }
    m = 8;
    __syncthreads();
  }

  const float* w1p = w1 + (size_t)e * DIM * INTER + lane;
  const float* w3p = w3 + (size_t)e * DIM * INTER + lane;
  const float* w2e = w2 + (size_t)e * INTER * DIM;
  const int d0 = w * 128;

  for (int base = 0; base < m; base += TTILE) {
    const int mt = min(TTILE, m - base);
    int tk[TTILE];
    #pragma unroll
    for (int t = 0; t < TTILE; ++t) tk[t] = lTok[base + t];

    // ---- phase A: wave w covers d in [d0,d0+128) for all 8 tokens ----
    float p1[TTILE], p3[TTILE];
    #pragma unroll
    for (int t = 0; t < TTILE; ++t) { p1[t] = 0.f; p3[t] = 0.f; }
    #pragma unroll 2
    for (int d = d0; d < d0 + 128; d += 4) {
      const float a0 = w1p[(d + 0) << 6];
      const float a1 = w1p[(d + 1) << 6];
      const float a2 = w1p[(d + 2) << 6];
      const float a3 = w1p[(d + 3) << 6];
      const float b0 = w3p[(d + 0) << 6];
      const float b1 = w3p[(d + 1) << 6];
      const float b2 = w3p[(d + 2) << 6];
      const float b3 = w3p[(d + 3) << 6];
      #pragma unroll
      for (int t = 0; t < TTILE; ++t) {
        const float4 xv = *(const float4*)(x + ((size_t)tk[t] << 9) + d);
        p1[t] += xv.x * a0 + xv.y * a1 + xv.z * a2 + xv.w * a3;
        p3[t] += xv.x * b0 + xv.y * b1 + xv.z * b2 + xv.w * b3;
      }
    }
    #pragma unroll
    for (int t = 0; t < TTILE; ++t) {
      part1[w][t][lane] = p1[t];
      part3[w][t][lane] = p3[t];
    }
    __syncthreads();

    // ---- reduce quarters + silu * h3 * route_weight -> as_ ----
    #pragma unroll
    for (int k = 0; k < 2; ++k) {
      const int idx = tid + k * 256;
      const int t = idx >> 6, ii = idx & 63;
      const float h1 = part1[0][t][ii] + part1[1][t][ii] +
                       part1[2][t][ii] + part1[3][t][ii];
      const float h3 = part3[0][t][ii] + part3[1][t][ii] +
                       part3[2][t][ii] + part3[3][t][ii];
      as_[t][ii] = (h1 / (1.0f + expf(-h1))) * h3 * lW[base + t];
    }
    __syncthreads();

    // ---- phase B: thread owns output cols tid and tid+256 ----
    // (next tile's post-A barrier protects as_/part: no trailing sync needed)
    float o0[TTILE], o1[TTILE];
    #pragma unroll
    for (int t = 0; t < TTILE; ++t) { o0[t] = 0.f; o1[t] = 0.f; }
    for (int ii = 0; ii < INTER; ii += 4) {
      const float u0 = w2e[(ii + 0) * DIM + tid];
      const float u1 = w2e[(ii + 1) * DIM + tid];
      const float u2 = w2e[(ii + 2) * DIM + tid];
      const float u3 = w2e[(ii + 3) * DIM + tid];
      const float v0 = w2e[(ii + 0) * DIM + tid + 256];
      const float v1 = w2e[(ii + 1) * DIM + tid + 256];
      const float v2 = w2e[(ii + 2) * DIM + tid + 256];
      const float v3 = w2e[(ii + 3) * DIM + tid + 256];
      #pragma unroll
      for (int t = 0; t < TTILE; ++t) {
        const float4 av = *(const float4*)&as_[t][ii];     // LDS broadcast
        o0[t] += av.x * u0 + av.y * u1 + av.z * u2 + av.w * u3;
        o1[t] += av.x * v0 + av.y * v1 + av.z * v2 + av.w * v3;
      }
    }
    for (int t = 0; t < mt; ++t) {
      atomicAdd(&out[(size_t)tk[t] * DIM + tid], o0[t]);
      atomicAdd(&out[(size_t)tk[t] * DIM + tid + 256], o1[t]);
    }
  }
}

extern "C" void kernel_launch(void* const* d_in, const int* in_sizes, int n_in,
                              void* d_out, int out_size, void* d_ws, size_t ws_size,
                              hipStream_t stream) {
  const float* x         = (const float*)d_in[0];
  const float* g_w       = (const float*)d_in[1];
  const float* gate_bias = (const float*)d_in[2];
  const float* w1        = (const float*)d_in[3];
  const float* w2        = (const float*)d_in[4];
  const float* w3        = (const float*)d_in[5];
  float* out = (float*)d_out;

  int*   chidx = (int*)d_ws;                        // 6144 ints
  float* chw   = (float*)((char*)d_ws + CHN * 4);   // 6144 floats

  gate_kernel<<<NTOK / 4, 256, 0, stream>>>(x, g_w, gate_bias, chidx, chw, out);
  ffn_kernel<<<N_ROUTED * GR + 2 * GS, 256, 0, stream>>>(
      x, w1, w2, w3, chidx, chw, out);
}

// Round 10
// 130.450 us; speedup vs baseline: 2.1017x; 2.1017x over previous
//
#include <hip/hip_runtime.h>
#include <math.h>

#define DIM 512
#define INTER 64
#define N_ROUTED 64
#define TOPK 6
#define NTOK 1024            // B*T
#define TTILE 16             // tokens per ffn tile
#define GR 8                 // blocks per routed expert (64*8 = 512)
#define GS 64                // blocks per shared expert (2*64 = 128)
#define CHN (NTOK * TOPK)    // 6144 dense choice entries
#define CHUNK (CHN / 256)    // 24 entries per thread in the list scan
#define CELLS (66 * 4096)    // b-frag cells per weight matrix (w1 or w3)
#define XPAD 524             // xsb row stride in bf16 elements (conflict-free b64)
#define ASTR 68              // as_ row stride in floats (aligned + conflict-free)

typedef __bf16 bf16x8 __attribute__((ext_vector_type(8)));
typedef __bf16 bf16x4 __attribute__((ext_vector_type(4)));
typedef float floatx4 __attribute__((ext_vector_type(4)));

__device__ __forceinline__ unsigned short f2bf(float f) {   // RNE fp32->bf16
  unsigned int u = __float_as_uint(f);
  u += 0x7FFF + ((u >> 16) & 1);
  return (unsigned short)(u >> 16);
}

// ---------------------------------------------------------------------------
// Gate (dispatch 1 of 2): one block per token (1024 blocks).
//  - zeroes this token's output row
//  - wave w computes experts [w*16,w*16+16) via coalesced g_w row loads +
//    butterfly reduce; wave 0: softmax + iterative top-6 argmax on
//    (prob+bias), first-index tie-break (matches lax.top_k)
//  - ALSO converts w1/w3 fp32 -> bf16 into the B-fragment-blocked layout
//    [e][kb(16)][quad(4)][n(64)][j(8)] used by the ffn MFMA phase
//    (grid-stride over 540672 cells; reads coalesced by n, writes 16B/thread)
// ---------------------------------------------------------------------------
__global__ __launch_bounds__(256) void gate_kernel(
    const float* __restrict__ x, const float* __restrict__ g_w,
    const float* __restrict__ gate_bias,
    const float* __restrict__ w1, const float* __restrict__ w3,
    int* __restrict__ chidx, float* __restrict__ chw,
    unsigned short* __restrict__ w1b, unsigned short* __restrict__ w3b,
    float* __restrict__ out) {
  __shared__ float logits[N_ROUTED];
  const int t = blockIdx.x;
  const int tid = threadIdx.x;
  const int lane = tid & 63;
  const int w = tid >> 6;

  if (tid < 128)
    ((float4*)(out + (size_t)t * DIM))[tid] = make_float4(0.f, 0.f, 0.f, 0.f);

  const float* xr = x + (size_t)t * DIM;
  const float4 xa = *(const float4*)(xr + lane * 4);
  const float4 xb = *(const float4*)(xr + 256 + lane * 4);

  #pragma unroll 4
  for (int k = 0; k < 16; ++k) {
    const int e = w * 16 + k;
    const float* gr = g_w + (size_t)e * DIM;
    const float4 ga = *(const float4*)(gr + lane * 4);
    const float4 gb = *(const float4*)(gr + 256 + lane * 4);
    float v = xa.x * ga.x + xa.y * ga.y + xa.z * ga.z + xa.w * ga.w
            + xb.x * gb.x + xb.y * gb.y + xb.z * gb.z + xb.w * gb.w;
    for (int off = 32; off; off >>= 1) v += __shfl_xor(v, off, 64);
    if (lane == 0) logits[e] = v;
  }
  __syncthreads();

  if (w == 0) {
    const float a = logits[lane];
    float m = a;
    for (int off = 32; off; off >>= 1) m = fmaxf(m, __shfl_xor(m, off, 64));
    const float p = expf(a - m);
    float s = p;
    for (int off = 32; off; off >>= 1) s += __shfl_xor(s, off, 64);
    const float prob = p / s;
    float biased = prob + gate_bias[lane];
    for (int k = 0; k < TOPK; ++k) {
      float v = biased;
      int idx = lane;
      for (int off = 1; off < 64; off <<= 1) {
        const float ov = __shfl_xor(v, off, 64);
        const int oi = __shfl_xor(idx, off, 64);
        if (ov > v || (ov == v && oi < idx)) { v = ov; idx = oi; }
      }
      if (lane == idx) {
        chidx[t * TOPK + k] = lane;
        chw[t * TOPK + k] = prob;      // ROUTE_SCALE == 1.0
        biased = -INFINITY;
      }
    }
  }

  // ---- weight conversion: fp32 -> bf16 B-frag blocked layout ----
  {
    const int gtid = blockIdx.x * 256 + tid;       // 0..262143
    for (int c = gtid; c < 2 * CELLS; c += NTOK * 256) {
      int cc = c;
      const float* src = w1;
      unsigned short* dst = w1b;
      if (cc >= CELLS) { cc -= CELLS; src = w3; dst = w3b; }
      const int n = cc & 63;
      const int quad = (cc >> 6) & 3;
      const int kb = (cc >> 8) & 15;
      const int e = cc >> 12;
      const float* s = src + (((size_t)e * 512 + kb * 32 + quad * 8) << 6) + n;
      unsigned int p0 = f2bf(s[0])       | ((unsigned int)f2bf(s[64])  << 16);
      unsigned int p1 = f2bf(s[2 * 64])  | ((unsigned int)f2bf(s[3 * 64]) << 16);
      unsigned int p2 = f2bf(s[4 * 64])  | ((unsigned int)f2bf(s[5 * 64]) << 16);
      unsigned int p3 = f2bf(s[6 * 64])  | ((unsigned int)f2bf(s[7 * 64]) << 16);
      *(uint4*)(dst + (size_t)cc * 8) = make_uint4(p0, p1, p2, p3);
    }
  }
}

// ---------------------------------------------------------------------------
// Expert FFN (dispatch 2 of 2): block = (expert, group), XCD-pinned
// (expert r only on XCD r%8 via blockIdx&7 round-robin heuristic).
// Routed blocks rebuild their token sub-list via deterministic block
// prefix-scan (all GR blocks agree on ranks; block g takes ranks==g mod GR).
// Phase A (MFMA bf16): stage 16 tokens' x as bf16 rows in LDS (stride XPAD,
// conflict-free b64 A-frag reads); wave w computes H1,H3[16 tok][16 inter]
// for inter cols [w*16,w*16+16) with 16x16x32 bf16 MFMA over K=512
// (16 kb-steps x 2 MFMA; A-frag m=lane&15,k=quad*8+j; B-frag from the
// blocked w1b/w3b, n=w*16+(lane&15)); silu(h1)*h3*route_w written from the
// C-layout (col=lane&15,row=quad*4+reg) into as_ (fp32, stride ASTR).
// Phase B (fp32 VALU, unchanged from r7): thread owns output cols
// (tid, tid+256), w2 fp32 streamed, coalesced atomicAdd into zeroed out.
// LDS ~22 KB; 2 barriers per tile.
// ---------------------------------------------------------------------------
__global__ __launch_bounds__(256, 4) void ffn_kernel(
    const float* __restrict__ x,
    const unsigned short* __restrict__ w1b,
    const unsigned short* __restrict__ w3b,
    const float* __restrict__ w2,
    const int* __restrict__ chidx, const float* __restrict__ chw,
    float* __restrict__ out) {
  __shared__ unsigned short xsb[16 * XPAD];   // 16.4 KB bf16 x-tile
  __shared__ float as_f[16 * ASTR];           // 4.3 KB activations
  __shared__ int   lTok[128];
  __shared__ float lW[128];
  __shared__ int   waveTot[4];

  const int tid = threadIdx.x;
  const int lane = tid & 63;
  const int w = tid >> 6;
  const int blk = blockIdx.x;

  int e, m;
  if (blk < N_ROUTED * GR) {
    // ---- routed: deterministic sub-list build ----
    const int c = blk & 7;          // XCD residue
    const int q = blk >> 3;         // 0..63
    const int ei = q >> 3;          // 0..7
    const int g = q & 7;            // group within expert
    const int r = ei * 8 + c;       // routed expert id (r%8 == c)
    e = r + 2;

    if (tid < 128) { lTok[tid] = 0; lW[tid] = 0.f; }

    const int j0 = tid * CHUNK;
    int cntL = 0;
    #pragma unroll
    for (int k = 0; k < CHUNK; ++k)
      cntL += (chidx[j0 + k] == r) ? 1 : 0;

    int incl = cntL;                // wave-inclusive prefix
    for (int off = 1; off < 64; off <<= 1) {
      const int v = __shfl_up(incl, off, 64);
      if (lane >= off) incl += v;
    }
    if (lane == 63) waveTot[w] = incl;
    __syncthreads();

    int waveOff = 0, nTot = 0;
    #pragma unroll
    for (int i = 0; i < 4; ++i) {
      const int v = waveTot[i];
      nTot += v;
      if (i < w) waveOff += v;
    }
    int rank = waveOff + incl - cntL;   // exclusive global rank
    for (int k = 0; k < CHUNK; ++k) {
      const int j = j0 + k;
      if (chidx[j] == r) {
        if ((rank & 7) == g) {
          lTok[rank >> 3] = j / TOPK;
          lW[rank >> 3] = chw[j];
        }
        ++rank;
      }
    }
    m = (nTot > g) ? ((nTot - g + 7) >> 3) : 0;
    __syncthreads();
  } else {
    // ---- shared experts: tokens g, g+64, ..., weight 1 ----
    const int sb = blk - N_ROUTED * GR;   // 0..127
    e = sb >> 6;
    const int g = sb & 63;
    if (tid < 128) {
      lTok[tid] = (tid < 16) ? (g + tid * GS) : 0;
      lW[tid] = (tid < 16) ? 1.0f : 0.f;
    }
    m = 16;
    __syncthreads();
  }

  const unsigned short* w1e = w1b + (size_t)e * 32768;
  const unsigned short* w3e = w3b + (size_t)e * 32768;
  const float* w2e = w2 + (size_t)e * INTER * DIM;

  const int nn = lane & 15;
  const int quad = lane >> 4;
  const unsigned short* xaBase = &xsb[nn * XPAD + quad * 8];
  const size_t bOff = (size_t)(quad * 64 + w * 16 + nn) * 8;

  for (int base = 0; base < m; base += TTILE) {
    const int mt = min(TTILE, m - base);

    // ---- stage 16 token rows as bf16 into xsb ----
    {
      const int row = tid >> 4;        // 0..15
      const int seg = tid & 15;        // 32 floats each
      const float* src = x + ((size_t)lTok[base + row] << 9) + seg * 32;
      unsigned short* dst = &xsb[row * XPAD + seg * 32];
      #pragma unroll
      for (int j = 0; j < 8; ++j) {
        const float4 v = *(const float4*)(src + j * 4);
        const unsigned int lo = f2bf(v.x) | ((unsigned int)f2bf(v.y) << 16);
        const unsigned int hi = f2bf(v.z) | ((unsigned int)f2bf(v.w) << 16);
        *(uint2*)(dst + j * 4) = make_uint2(lo, hi);
      }
    }
    __syncthreads();

    // ---- phase A: MFMA over K=512; wave w -> inter cols [w*16,w*16+16) ----
    {
      floatx4 acc1 = {0.f, 0.f, 0.f, 0.f};
      floatx4 acc3 = {0.f, 0.f, 0.f, 0.f};
      #pragma unroll 4
      for (int kb = 0; kb < 16; ++kb) {
        union { bf16x8 v8; bf16x4 h[2]; } au;
        au.h[0] = *(const bf16x4*)(xaBase + kb * 32);
        au.h[1] = *(const bf16x4*)(xaBase + kb * 32 + 4);
        const bf16x8 b1 = *(const bf16x8*)(w1e + bOff + (size_t)kb * 2048);
        const bf16x8 b3 = *(const bf16x8*)(w3e + bOff + (size_t)kb * 2048);
        acc1 = __builtin_amdgcn_mfma_f32_16x16x32_bf16(au.v8, b1, acc1, 0, 0, 0);
        acc3 = __builtin_amdgcn_mfma_f32_16x16x32_bf16(au.v8, b3, acc3, 0, 0, 0);
      }
      #pragma unroll
      for (int r = 0; r < 4; ++r) {
        const int row = quad * 4 + r;         // C/D: row = quad*4 + reg
        const float h1 = acc1[r];
        const float h3 = acc3[r];
        as_f[row * ASTR + w * 16 + nn] =
            (h1 / (1.f + expf(-h1))) * h3 * lW[base + row];
      }
    }
    __syncthreads();

    // ---- phase B (fp32): thread owns output cols tid and tid+256 ----
    // (next tile's post-staging barrier protects as_f: no trailing sync)
    float o0[TTILE], o1[TTILE];
    #pragma unroll
    for (int t = 0; t < TTILE; ++t) { o0[t] = 0.f; o1[t] = 0.f; }
    for (int ii = 0; ii < INTER; ii += 4) {
      const float u0 = w2e[(ii + 0) * DIM + tid];
      const float u1 = w2e[(ii + 1) * DIM + tid];
      const float u2 = w2e[(ii + 2) * DIM + tid];
      const float u3 = w2e[(ii + 3) * DIM + tid];
      const float v0 = w2e[(ii + 0) * DIM + tid + 256];
      const float v1 = w2e[(ii + 1) * DIM + tid + 256];
      const float v2 = w2e[(ii + 2) * DIM + tid + 256];
      const float v3 = w2e[(ii + 3) * DIM + tid + 256];
      #pragma unroll
      for (int t = 0; t < TTILE; ++t) {
        const float4 av = *(const float4*)&as_f[t * ASTR + ii];  // broadcast
        o0[t] += av.x * u0 + av.y * u1 + av.z * u2 + av.w * u3;
        o1[t] += av.x * v0 + av.y * v1 + av.z * v2 + av.w * v3;
      }
    }
    for (int t = 0; t < mt; ++t) {
      const int tok = lTok[base + t];
      atomicAdd(&out[(size_t)tok * DIM + tid], o0[t]);
      atomicAdd(&out[(size_t)tok * DIM + tid + 256], o1[t]);
    }
  }
}

extern "C" void kernel_launch(void* const* d_in, const int* in_sizes, int n_in,
                              void* d_out, int out_size, void* d_ws, size_t ws_size,
                              hipStream_t stream) {
  const float* x         = (const float*)d_in[0];
  const float* g_w       = (const float*)d_in[1];
  const float* gate_bias = (const float*)d_in[2];
  const float* w1        = (const float*)d_in[3];
  const float* w2        = (const float*)d_in[4];
  const float* w3        = (const float*)d_in[5];
  float* out = (float*)d_out;

  char* ws = (char*)d_ws;
  int*            chidx = (int*)ws;                              // 24576 B
  float*          chw   = (float*)(ws + 24576);                  // 24576 B
  unsigned short* w1b   = (unsigned short*)(ws + 49152);         // 4,325,376 B
  unsigned short* w3b   = (unsigned short*)(ws + 49152 + (size_t)CELLS * 16);

  gate_kernel<<<NTOK, 256, 0, stream>>>(x, g_w, gate_bias, w1, w3,
                                        chidx, chw, w1b, w3b, out);
  ffn_kernel<<<N_ROUTED * GR + 2 * GS, 256, 0, stream>>>(
      x, w1b, w3b, w2, chidx, chw, out);
}

// Round 11
// 119.043 us; speedup vs baseline: 2.3031x; 1.0958x over previous
//
#include <hip/hip_runtime.h>
#include <math.h>

#define DIM 512
#define INTER 64
#define N_ROUTED 64
#define TOPK 6
#define NTOK 1024            // B*T
#define TTILE 16             // tokens per ffn tile
#define GR 8                 // blocks per routed expert (64*8 = 512)
#define GS 64                // blocks per shared expert (2*64 = 128)
#define CHN (NTOK * TOPK)    // 6144 dense choice entries
#define CHUNK (CHN / 256)    // 24 entries per thread in the list scan
#define CELLS 270336         // b-frag cells per matrix (w1: 66*16*4*64, w2: 66*2*4*512)
#define XPAD 520             // xsb row stride (bf16)
#define ASTRB 72             // asb row stride (bf16)

typedef __bf16 bf16x8 __attribute__((ext_vector_type(8)));
typedef __bf16 bf16x4 __attribute__((ext_vector_type(4)));
typedef float floatx4 __attribute__((ext_vector_type(4)));

__device__ __forceinline__ unsigned short f2bf(float f) {   // RNE fp32->bf16
  unsigned int u = __float_as_uint(f);
  u += 0x7FFF + ((u >> 16) & 1);
  return (unsigned short)(u >> 16);
}

// ---------------------------------------------------------------------------
// Gate (dispatch 1 of 2): one block per token (1024 blocks).
//  - zeroes this token's output row
//  - wave w computes experts [w*16,w*16+16) via coalesced g_w row loads +
//    butterfly reduce; wave 0: fp32 softmax + iterative top-6 argmax on
//    (prob+bias), first-index tie-break (matches lax.top_k)
//  - converts w1/w3/w2 fp32 -> bf16 B-frag-blocked layouts for the ffn MFMAs
//    (grid-stride over 3*CELLS cells; reads coalesced, 16B writes)
// ---------------------------------------------------------------------------
__global__ __launch_bounds__(256) void gate_kernel(
    const float* __restrict__ x, const float* __restrict__ g_w,
    const float* __restrict__ gate_bias,
    const float* __restrict__ w1, const float* __restrict__ w3,
    const float* __restrict__ w2,
    int* __restrict__ chidx, float* __restrict__ chw,
    unsigned short* __restrict__ w1b, unsigned short* __restrict__ w3b,
    unsigned short* __restrict__ w2b,
    float* __restrict__ out) {
  __shared__ float logits[N_ROUTED];
  const int t = blockIdx.x;
  const int tid = threadIdx.x;
  const int lane = tid & 63;
  const int w = tid >> 6;

  if (tid < 128)
    ((float4*)(out + (size_t)t * DIM))[tid] = make_float4(0.f, 0.f, 0.f, 0.f);

  const float* xr = x + (size_t)t * DIM;
  const float4 xa = *(const float4*)(xr + lane * 4);
  const float4 xb = *(const float4*)(xr + 256 + lane * 4);

  #pragma unroll 4
  for (int k = 0; k < 16; ++k) {
    const int e = w * 16 + k;
    const float* gr = g_w + (size_t)e * DIM;
    const float4 ga = *(const float4*)(gr + lane * 4);
    const float4 gb = *(const float4*)(gr + 256 + lane * 4);
    float v = xa.x * ga.x + xa.y * ga.y + xa.z * ga.z + xa.w * ga.w
            + xb.x * gb.x + xb.y * gb.y + xb.z * gb.z + xb.w * gb.w;
    for (int off = 32; off; off >>= 1) v += __shfl_xor(v, off, 64);
    if (lane == 0) logits[e] = v;
  }
  __syncthreads();

  if (w == 0) {
    const float a = logits[lane];
    float m = a;
    for (int off = 32; off; off >>= 1) m = fmaxf(m, __shfl_xor(m, off, 64));
    const float p = expf(a - m);
    float s = p;
    for (int off = 32; off; off >>= 1) s += __shfl_xor(s, off, 64);
    const float prob = p / s;
    float biased = prob + gate_bias[lane];
    for (int k = 0; k < TOPK; ++k) {
      float v = biased;
      int idx = lane;
      for (int off = 1; off < 64; off <<= 1) {
        const float ov = __shfl_xor(v, off, 64);
        const int oi = __shfl_xor(idx, off, 64);
        if (ov > v || (ov == v && oi < idx)) { v = ov; idx = oi; }
      }
      if (lane == idx) {
        chidx[t * TOPK + k] = lane;
        chw[t * TOPK + k] = prob;      // ROUTE_SCALE == 1.0
        biased = -INFINITY;
      }
    }
  }

  // ---- weight conversion: fp32 -> bf16 B-frag blocked layouts ----
  // w1/w3 cell [e][kb16][quad][n64][j8]: elem = w[e][kb*32+quad*8+j][n]
  // w2  cell [e][kb2][quad][col512][j8]: elem = w2[e][kb*32+quad*8+j][col]
  {
    const int gtid = blockIdx.x * 256 + tid;       // 0..262143
    for (int c = gtid; c < 3 * CELLS; c += NTOK * 256) {
      const float* s;
      unsigned short* dst;
      int cc = c, stride;
      if (cc < 2 * CELLS) {
        const float* src = w1;
        dst = w1b;
        if (cc >= CELLS) { cc -= CELLS; src = w3; dst = w3b; }
        const int n = cc & 63;
        const int quad = (cc >> 6) & 3;
        const int kb = (cc >> 8) & 15;
        const int e = cc >> 12;
        s = src + (((size_t)e * 512 + kb * 32 + quad * 8) << 6) + n;
        stride = 64;
        dst += (size_t)cc * 8;
      } else {
        cc -= 2 * CELLS;
        const int col = cc & 511;
        const int quad = (cc >> 9) & 3;
        const int kb = (cc >> 11) & 1;
        const int e = cc >> 12;
        s = w2 + ((size_t)e * 64 + kb * 32 + quad * 8) * 512 + col;
        stride = 512;
        dst = w2b + (size_t)cc * 8;
      }
      unsigned int p0 = f2bf(s[0])          | ((unsigned int)f2bf(s[stride])     << 16);
      unsigned int p1 = f2bf(s[2 * stride]) | ((unsigned int)f2bf(s[3 * stride]) << 16);
      unsigned int p2 = f2bf(s[4 * stride]) | ((unsigned int)f2bf(s[5 * stride]) << 16);
      unsigned int p3 = f2bf(s[6 * stride]) | ((unsigned int)f2bf(s[7 * stride]) << 16);
      *(uint4*)dst = make_uint4(p0, p1, p2, p3);
    }
  }
}

// ---------------------------------------------------------------------------
// Expert FFN (dispatch 2 of 2): block = (expert, group), XCD-pinned
// (expert r only on XCD r%8 via blockIdx&7 round-robin heuristic).
// Routed blocks rebuild their token sub-list via deterministic block
// prefix-scan (all GR blocks agree on ranks; block g takes ranks==g mod GR).
// Phase A (MFMA): x tile staged as bf16 (coalesced fidx loads, 2-way-free
// stores); wave w computes H1,H3 for inter cols [w*16,w*16+16) with
// 16x16x32 bf16 MFMA over K=512; silu(h1)*h3*route_w written bf16 into asb
// (A-frag-readable layout).
// Phase B (MFMA): out_tile[16x512] = asb[16x64] @ w2b[64x512]; wave w covers
// cols [w*128,w*128+128): 2 A-frags + 8 col-tiles x 2 MFMA; C-layout
// (col=lane&15, row=quad*4+reg) scattered with row<mt predicated atomicAdd.
// LDS ~19.4 KB; 2 barriers per tile.
// ---------------------------------------------------------------------------
__global__ __launch_bounds__(256, 4) void ffn_kernel(
    const float* __restrict__ x,
    const unsigned short* __restrict__ w1b,
    const unsigned short* __restrict__ w3b,
    const unsigned short* __restrict__ w2b,
    const int* __restrict__ chidx, const float* __restrict__ chw,
    float* __restrict__ out) {
  __shared__ unsigned short xsb[16 * XPAD];   // 16.3 KB bf16 x-tile
  __shared__ unsigned short asb[16 * ASTRB];  // 2.25 KB bf16 activations
  __shared__ int   lTok[128];
  __shared__ float lW[128];
  __shared__ int   waveTot[4];

  const int tid = threadIdx.x;
  const int lane = tid & 63;
  const int w = tid >> 6;
  const int blk = blockIdx.x;

  int e, m;
  if (blk < N_ROUTED * GR) {
    // ---- routed: deterministic sub-list build ----
    const int c = blk & 7;          // XCD residue
    const int q = blk >> 3;         // 0..63
    const int ei = q >> 3;          // 0..7
    const int g = q & 7;            // group within expert
    const int r = ei * 8 + c;       // routed expert id (r%8 == c)
    e = r + 2;

    if (tid < 128) { lTok[tid] = 0; lW[tid] = 0.f; }

    const int j0 = tid * CHUNK;
    int cntL = 0;
    #pragma unroll
    for (int k = 0; k < CHUNK; ++k)
      cntL += (chidx[j0 + k] == r) ? 1 : 0;

    int incl = cntL;                // wave-inclusive prefix
    for (int off = 1; off < 64; off <<= 1) {
      const int v = __shfl_up(incl, off, 64);
      if (lane >= off) incl += v;
    }
    if (lane == 63) waveTot[w] = incl;
    __syncthreads();

    int waveOff = 0, nTot = 0;
    #pragma unroll
    for (int i = 0; i < 4; ++i) {
      const int v = waveTot[i];
      nTot += v;
      if (i < w) waveOff += v;
    }
    int rank = waveOff + incl - cntL;   // exclusive global rank
    for (int k = 0; k < CHUNK; ++k) {
      const int j = j0 + k;
      if (chidx[j] == r) {
        if ((rank & 7) == g) {
          lTok[rank >> 3] = j / TOPK;
          lW[rank >> 3] = chw[j];
        }
        ++rank;
      }
    }
    m = (nTot > g) ? ((nTot - g + 7) >> 3) : 0;
    __syncthreads();
  } else {
    // ---- shared experts: tokens g, g+64, ..., weight 1 ----
    const int sb = blk - N_ROUTED * GR;   // 0..127
    e = sb >> 6;
    const int g = sb & 63;
    if (tid < 128) {
      lTok[tid] = (tid < 16) ? (g + tid * GS) : 0;
      lW[tid] = (tid < 16) ? 1.0f : 0.f;
    }
    m = 16;
    __syncthreads();
  }

  const unsigned short* w1e = w1b + (size_t)e * 32768;
  const unsigned short* w3e = w3b + (size_t)e * 32768;
  const unsigned short* w2e = w2b + (size_t)e * 32768;

  const int nn = lane & 15;
  const int quad = lane >> 4;
  const unsigned short* xaBase = &xsb[nn * XPAD + quad * 8];
  const size_t bOff = (size_t)(quad * 64 + w * 16 + nn) * 8;

  for (int base = 0; base < m; base += TTILE) {
    const int mt = min(TTILE, m - base);

    // ---- stage 16 token rows as bf16 into xsb (coalesced float4 loads) ----
    #pragma unroll
    for (int k = 0; k < 8; ++k) {
      const int fidx = tid + k * 256;     // 0..2047 float4 slots
      const int row = fidx >> 7;          // 128 float4 per row
      const int c4 = fidx & 127;
      const float4 v = *(const float4*)(x + ((size_t)lTok[base + row] << 9) + c4 * 4);
      const unsigned int lo = f2bf(v.x) | ((unsigned int)f2bf(v.y) << 16);
      const unsigned int hi = f2bf(v.z) | ((unsigned int)f2bf(v.w) << 16);
      *(uint2*)&xsb[row * XPAD + c4 * 4] = make_uint2(lo, hi);
    }
    __syncthreads();

    // ---- phase A: MFMA over K=512; wave w -> inter cols [w*16,w*16+16) ----
    {
      floatx4 acc1 = {0.f, 0.f, 0.f, 0.f};
      floatx4 acc3 = {0.f, 0.f, 0.f, 0.f};
      #pragma unroll 4
      for (int kb = 0; kb < 16; ++kb) {
        union { bf16x8 v8; bf16x4 h[2]; } au;
        au.h[0] = *(const bf16x4*)(xaBase + kb * 32);
        au.h[1] = *(const bf16x4*)(xaBase + kb * 32 + 4);
        const bf16x8 b1 = *(const bf16x8*)(w1e + bOff + (size_t)kb * 2048);
        const bf16x8 b3 = *(const bf16x8*)(w3e + bOff + (size_t)kb * 2048);
        acc1 = __builtin_amdgcn_mfma_f32_16x16x32_bf16(au.v8, b1, acc1, 0, 0, 0);
        acc3 = __builtin_amdgcn_mfma_f32_16x16x32_bf16(au.v8, b3, acc3, 0, 0, 0);
      }
      #pragma unroll
      for (int r = 0; r < 4; ++r) {
        const int row = quad * 4 + r;         // C/D: row = quad*4 + reg
        const float h1 = acc1[r];
        const float h3 = acc3[r];
        asb[row * ASTRB + w * 16 + nn] =
            f2bf((h1 / (1.f + expf(-h1))) * h3 * lW[base + row]);
      }
    }
    __syncthreads();

    // ---- phase B: MFMA out_tile = asb @ w2b; wave w -> cols [w*128,+128) ----
    {
      const bf16x8 a0 = *(const bf16x8*)&asb[nn * ASTRB + quad * 8];
      const bf16x8 a1 = *(const bf16x8*)&asb[nn * ASTRB + 32 + quad * 8];
      floatx4 acc[8];
      #pragma unroll
      for (int ct = 0; ct < 8; ++ct) acc[ct] = (floatx4){0.f, 0.f, 0.f, 0.f};
      #pragma unroll
      for (int ct = 0; ct < 8; ++ct) {
        const int col = w * 128 + ct * 16 + nn;
        const bf16x8 b0 = *(const bf16x8*)(w2e + ((size_t)(0 * 4 + quad) * 512 + col) * 8);
        const bf16x8 b1 = *(const bf16x8*)(w2e + ((size_t)(1 * 4 + quad) * 512 + col) * 8);
        acc[ct] = __builtin_amdgcn_mfma_f32_16x16x32_bf16(a0, b0, acc[ct], 0, 0, 0);
        acc[ct] = __builtin_amdgcn_mfma_f32_16x16x32_bf16(a1, b1, acc[ct], 0, 0, 0);
      }
      int tokr[4];
      #pragma unroll
      for (int r = 0; r < 4; ++r) tokr[r] = lTok[base + quad * 4 + r];
      #pragma unroll
      for (int r = 0; r < 4; ++r) {
        if (quad * 4 + r < mt) {
          float* op = out + ((size_t)tokr[r] << 9) + w * 128 + nn;
          #pragma unroll
          for (int ct = 0; ct < 8; ++ct)
            atomicAdd(op + ct * 16, acc[ct][r]);
        }
      }
    }
  }
}

extern "C" void kernel_launch(void* const* d_in, const int* in_sizes, int n_in,
                              void* d_out, int out_size, void* d_ws, size_t ws_size,
                              hipStream_t stream) {
  const float* x         = (const float*)d_in[0];
  const float* g_w       = (const float*)d_in[1];
  const float* gate_bias = (const float*)d_in[2];
  const float* w1        = (const float*)d_in[3];
  const float* w2        = (const float*)d_in[4];
  const float* w3        = (const float*)d_in[5];
  float* out = (float*)d_out;

  char* ws = (char*)d_ws;
  int*            chidx = (int*)ws;                              // 24576 B
  float*          chw   = (float*)(ws + 24576);                  // 24576 B
  unsigned short* w1b   = (unsigned short*)(ws + 49152);
  unsigned short* w3b   = (unsigned short*)(ws + 49152 + (size_t)CELLS * 16);
  unsigned short* w2b   = (unsigned short*)(ws + 49152 + (size_t)CELLS * 32);

  gate_kernel<<<NTOK, 256, 0, stream>>>(x, g_w, gate_bias, w1, w3, w2,
                                        chidx, chw, w1b, w3b, w2b, out);
  ffn_kernel<<<N_ROUTED * GR + 2 * GS, 256, 0, stream>>>(
      x, w1b, w3b, w2b, chidx, chw, out);
}